// Round 1
// baseline (156.753 us; speedup 1.0000x reference)
//
#include <hip/hip_runtime.h>
#include <math.h>

#define BATCH 32
#define HH 512
#define WW 512
#define NC 32        // cells per side
#define NORI 6
#define CH 262144    // HH*WW channel stride (floats)

// ---- round-5-verbatim numpy downstream (cold path, ONE inline copy) ----
__device__ __forceinline__ int bin_of(float a) {
    const float deg = __fmul_rn(a, 57.29577951308232f);
    float m = fmodf(deg, 180.0f);
    if (m < 0.0f) m = __fadd_rn(m, 180.0f);
    const int b = (int)floorf(__fdiv_rn(m, 30.0f));
    return min(max(b, 0), NORI - 1);
}
__device__ __forceinline__ float ulp_step(float x, int k) {
    const int i = __float_as_int(x);
    int key = (i >= 0) ? i : -(i & 0x7FFFFFFF);
    key += k;
    const int r = (key >= 0) ? key : (int)(0x80000000u | (unsigned)(-key));
    return __int_as_float(r);
}
__device__ __forceinline__ void deposit(float acc[NORI], int bin, float val) {
#pragma unroll
    for (int o = 0; o < NORI; ++o) acc[o] += (bin == o) ? val : 0.0f;
}
// (0.299*R + 0.587*G) + 0.114*B, f32, no FMA contraction
__device__ __forceinline__ float gray_comb(float r, float g, float b) {
    return __fadd_rn(__fadd_rn(__fmul_rn(0.299f, r), __fmul_rn(0.587f, g)),
                     __fmul_rn(0.114f, b));
}
__device__ __forceinline__ float gray_i(const float* __restrict__ img, int off) {
    return gray_comb(img[off], img[off + CH], img[off + 2 * CH]);
}
__device__ __forceinline__ float4 gray4(const float* __restrict__ img, int off) {
    const float4 r = *(const float4*)(img + off);
    const float4 g = *(const float4*)(img + off + CH);
    const float4 b = *(const float4*)(img + off + 2 * CH);
    float4 o;
    o.x = gray_comb(r.x, g.x, b.x);
    o.y = gray_comb(r.y, g.y, b.y);
    o.z = gray_comb(r.z, g.z, b.z);
    o.w = gray_comb(r.w, g.w, b.w);
    return o;
}

__device__ __forceinline__ void hot_pixel(float gy, float gx, int bitk,
                                          float acc[NORI], unsigned& ambmask) {
    const float mag = __fsqrt_rn(__fmaf_rn(gy, gy, __fmul_rn(gx, gx)));
    // canonicalize to theta in [0,180)
    const bool neg = gy < 0.0f;
    const float cy = fabsf(gy);
    const float cx = neg ? -gx : gx;
    // t_i ~ sin(theta - alpha_i), alpha = 30,60,90,120,150 (shared products)
    const float pa = __fmul_rn(cy, 0.86602540378443864676f);
    const float pb = __fmul_rn(cx, 0.5f);
    const float pc = __fmul_rn(cy, 0.5f);
    const float pd = __fmul_rn(cx, 0.86602540378443864676f);
    const float t1 = __fsub_rn(pa, pb);
    const float t2 = __fsub_rn(pc, pd);
    const float t3 = -cx;
    const float t4 = -__fadd_rn(pc, pd);
    const float t5 = -__fadd_rn(pa, pb);
    int bin = (t1 >= 0.0f) + (t2 >= 0.0f) + (t3 >= 0.0f) +
              (t4 >= 0.0f) + (t5 >= 0.0f);
    const float s = __fmul_rn(mag, 1e-5f);
    const float mn = fminf(fminf(fminf(fabsf(t1), fabsf(t2)),
                                 fminf(fabsf(t3), fabsf(t4))), fabsf(t5));
    bool amb = (mn < s) || (cx < 0.0f && cy < s);   // incl. wrap at 180
    if (gy == 0.0f) { bin = 0; amb = false; }       // deterministic (r3/r5)
    else if (gx == 0.0f) { bin = 3; amb = false; }
    ambmask |= amb ? (1u << bitk) : 0u;
    deposit(acc, bin, amb ? 0.0f : mag);
}

// Wave = full 512-col row span: lane owns 8 adjacent cols (2x float4 per
// channel), 4 rows per wave; block = 4 waves = one 16-row cell row x 512 cols.
// No halo global loads at all: lane-edge gx columns come from 2 shfls/row,
// image borders give gx=0 / gy=0. Rolling 3-row gray window (2x float4).
// Ambiguous pixels (within 1e-5 rad of a bin boundary) set a mask bit and are
// re-done post-loop with the round-5 atan2f +-2ulp policy from global memory.
__global__ __launch_bounds__(256) void hog_cells_kernel(const float* __restrict__ x,
                                                        float* __restrict__ cells) {
    const int b = blockIdx.y;
    const int cr = blockIdx.x;              // cell row
    const int tid = threadIdx.x;
    const int wave = tid >> 6, lane = tid & 63;
    const int R0 = cr * 16 + wave * 4;      // this wave's first pixel row
    const int c0 = lane * 8;                // this lane's first column
    const float* img = x + (size_t)b * 3 * HH * WW;

    __shared__ float hist[NC][NORI];
    if (tid < NC * NORI) ((float*)hist)[tid] = 0.0f;
    __syncthreads();

    const int rm = max(R0 - 1, 0);
    float4 gm1a = gray4(img, rm * WW + c0);
    float4 gm1b = gray4(img, rm * WW + c0 + 4);
    float4 g0a  = gray4(img, R0 * WW + c0);
    float4 g0b  = gray4(img, R0 * WW + c0 + 4);

    float acc[NORI] = {0, 0, 0, 0, 0, 0};
    unsigned ambmask = 0;

#pragma unroll
    for (int k = 0; k < 4; ++k) {
        const int r = R0 + k;
        const int rn = min(r + 1, HH - 1);
        const float4 gp1a = gray4(img, rn * WW + c0);
        const float4 gp1b = gray4(img, rn * WW + c0 + 4);

        const bool row_ok = (r >= 1) && (r < HH - 1);
        const float gy0 = row_ok ? __fsub_rn(gp1a.x, gm1a.x) : 0.0f;
        const float gy1 = row_ok ? __fsub_rn(gp1a.y, gm1a.y) : 0.0f;
        const float gy2 = row_ok ? __fsub_rn(gp1a.z, gm1a.z) : 0.0f;
        const float gy3 = row_ok ? __fsub_rn(gp1a.w, gm1a.w) : 0.0f;
        const float gy4 = row_ok ? __fsub_rn(gp1b.x, gm1b.x) : 0.0f;
        const float gy5 = row_ok ? __fsub_rn(gp1b.y, gm1b.y) : 0.0f;
        const float gy6 = row_ok ? __fsub_rn(gp1b.z, gm1b.z) : 0.0f;
        const float gy7 = row_ok ? __fsub_rn(gp1b.w, gm1b.w) : 0.0f;

        const float left  = __shfl(g0b.w, (lane + 63) & 63);  // prev lane col 7
        const float right = __shfl(g0a.x, (lane + 1) & 63);   // next lane col 0

        const float gx0 = (lane == 0)  ? 0.0f : __fsub_rn(g0a.y, left);
        const float gx1 = __fsub_rn(g0a.z, g0a.x);
        const float gx2 = __fsub_rn(g0a.w, g0a.y);
        const float gx3 = __fsub_rn(g0b.x, g0a.z);
        const float gx4 = __fsub_rn(g0b.y, g0a.w);
        const float gx5 = __fsub_rn(g0b.z, g0b.x);
        const float gx6 = __fsub_rn(g0b.w, g0b.y);
        const float gx7 = (lane == 63) ? 0.0f : __fsub_rn(right, g0b.z);

        hot_pixel(gy0, gx0, 8 * k + 0, acc, ambmask);
        hot_pixel(gy1, gx1, 8 * k + 1, acc, ambmask);
        hot_pixel(gy2, gx2, 8 * k + 2, acc, ambmask);
        hot_pixel(gy3, gx3, 8 * k + 3, acc, ambmask);
        hot_pixel(gy4, gx4, 8 * k + 4, acc, ambmask);
        hot_pixel(gy5, gx5, 8 * k + 5, acc, ambmask);
        hot_pixel(gy6, gx6, 8 * k + 6, acc, ambmask);
        hot_pixel(gy7, gx7, 8 * k + 7, acc, ambmask);

        gm1a = g0a; gm1b = g0b; g0a = gp1a; g0b = gp1b;
    }

    // cold phase: rare. amb pixels are interior with gy!=0 && gx!=0;
    // recompute bitwise-identically from global memory.
    if (__any(ambmask != 0)) {
        unsigned m = ambmask;
        while (m) {
            const int bit = __builtin_ctz(m);
            m &= m - 1;
            const int r = R0 + (bit >> 3);
            const int c = c0 + (bit & 7);
            const int off = r * WW + c;
            const float gy = __fsub_rn(gray_i(img, off + WW), gray_i(img, off - WW));
            const float gx = __fsub_rn(gray_i(img, off + 1), gray_i(img, off - 1));
            const float mag = __fsqrt_rn(__fmaf_rn(gy, gy, __fmul_rn(gx, gx)));
            const float a = atan2f(gy, gx);
            const int bl = bin_of(ulp_step(a, -2));
            const int bh = bin_of(ulp_step(a, +2));
            if (bl == bh) {
                deposit(acc, bl, mag);
            } else {
                const int b0 = bin_of(a);
                const int bo = (b0 == bl) ? bh : bl;
                deposit(acc, b0, __fmul_rn(mag, 0.65f));
                deposit(acc, bo, __fmul_rn(mag, 0.35f));
            }
        }
    }

    // lane pair (2c, 2c+1) covers cell c's 16 columns: one xor-1 reduce
#pragma unroll
    for (int o = 0; o < NORI; ++o) {
        float v = acc[o];
        v += __shfl_xor(v, 1);
        acc[o] = v;
    }
    if ((lane & 1) == 0) {
        const int cell = lane >> 1;
#pragma unroll
        for (int o = 0; o < NORI; ++o) atomicAdd(&hist[cell][o], acc[o]);
    }
    __syncthreads();
    if (tid < NC * NORI) {
        const int cell = tid / 6, o = tid - cell * 6;
        cells[(((size_t)b * NC + cr) * NC + cell) * NORI + o] =
            hist[cell][o] * (1.0f / 256.0f);
    }
}

// One thread per (b, block_row, block_col): float2 loads, L2-Hys normalize.
__global__ __launch_bounds__(256) void hog_norm_kernel(const float* __restrict__ cells,
                                                       float* __restrict__ out) {
    const int idx = blockIdx.x * 256 + threadIdx.x;
    const int total = BATCH * 31 * 31;
    if (idx >= total) return;
    const int bc = idx % 31;
    const int t = idx / 31;
    const int br = t % 31;
    const int b = t / 31;

    const float* cb = cells + (size_t)b * NC * NC * NORI;
    const float2* p0 = (const float2*)(cb + ((br) * NC + bc) * NORI);
    const float2* p1 = (const float2*)(cb + ((br + 1) * NC + bc) * NORI);
    float v[24];
#pragma unroll
    for (int q = 0; q < 6; ++q) {
        const float2 r0 = p0[q], r1 = p1[q];
        v[2 * q] = r0.x; v[2 * q + 1] = r0.y;
        v[12 + 2 * q] = r1.x; v[12 + 2 * q + 1] = r1.y;
    }
    float ss = 0.0f;
#pragma unroll
    for (int k = 0; k < 24; ++k) ss = __fadd_rn(ss, __fmul_rn(v[k], v[k]));
    const float n1 = __fsqrt_rn(__fadd_rn(ss, 1e-10f));  // EPS^2, EPS=1e-5
    float ss2 = 0.0f;
#pragma unroll
    for (int k = 0; k < 24; ++k) {
        v[k] = fminf(__fdiv_rn(v[k], n1), 0.2f);
        ss2 = __fadd_rn(ss2, __fmul_rn(v[k], v[k]));
    }
    const float n2 = __fsqrt_rn(__fadd_rn(ss2, 1e-10f));
    float* op = out + (size_t)idx * 24;
#pragma unroll
    for (int k = 0; k < 24; ++k) op[k] = __fdiv_rn(v[k], n2);
}

extern "C" void kernel_launch(void* const* d_in, const int* in_sizes, int n_in,
                              void* d_out, int out_size, void* d_ws, size_t ws_size,
                              hipStream_t stream) {
    const float* x = (const float*)d_in[0];
    float* out = (float*)d_out;
    float* cells = (float*)d_ws;  // BATCH*32*32*6 floats = 786 KB

    dim3 g1(NC, BATCH), b1(256);
    hog_cells_kernel<<<g1, b1, 0, stream>>>(x, cells);

    const int total = BATCH * 31 * 31;
    hog_norm_kernel<<<(total + 255) / 256, 256, 0, stream>>>(cells, out);
}

// Round 2
// 153.672 us; speedup vs baseline: 1.0201x; 1.0201x over previous
//
#include <hip/hip_runtime.h>
#include <math.h>

#define BATCH 32
#define HH 512
#define WW 512
#define NC 32        // cells per side
#define NORI 6
#define CH 262144    // HH*WW channel stride (floats)

// ---- round-5-verbatim numpy downstream (cold path, ONE inline copy) ----
__device__ __forceinline__ int bin_of(float a) {
    const float deg = __fmul_rn(a, 57.29577951308232f);
    float m = fmodf(deg, 180.0f);
    if (m < 0.0f) m = __fadd_rn(m, 180.0f);
    const int b = (int)floorf(__fdiv_rn(m, 30.0f));
    return min(max(b, 0), NORI - 1);
}
__device__ __forceinline__ float ulp_step(float x, int k) {
    const int i = __float_as_int(x);
    int key = (i >= 0) ? i : -(i & 0x7FFFFFFF);
    key += k;
    const int r = (key >= 0) ? key : (int)(0x80000000u | (unsigned)(-key));
    return __int_as_float(r);
}
// cumulative-form deposit: adding `val` to bin b == adding val to s_0..s_b
// (hist[o] is recovered as s_o - s_{o+1} at the final write)
__device__ __forceinline__ void deposit_s(float s[NORI], int bin, float val) {
#pragma unroll
    for (int o = 0; o < NORI; ++o) s[o] += (o <= bin) ? val : 0.0f;
}
// (0.299*R + 0.587*G) + 0.114*B, f32, no FMA contraction
__device__ __forceinline__ float gray_comb(float r, float g, float b) {
    return __fadd_rn(__fadd_rn(__fmul_rn(0.299f, r), __fmul_rn(0.587f, g)),
                     __fmul_rn(0.114f, b));
}
__device__ __forceinline__ float gray_i(const float* __restrict__ img, int off) {
    return gray_comb(img[off], img[off + CH], img[off + 2 * CH]);
}
__device__ __forceinline__ float4 gray4(const float* __restrict__ img, int off) {
    const float4 r = *(const float4*)(img + off);
    const float4 g = *(const float4*)(img + off + CH);
    const float4 b = *(const float4*)(img + off + 2 * CH);
    float4 o;
    o.x = gray_comb(r.x, g.x, b.x);
    o.y = gray_comb(r.y, g.y, b.y);
    o.z = gray_comb(r.z, g.z, b.z);
    o.w = gray_comb(r.w, g.w, b.w);
    return o;
}

// Cumulative-bin accumulation: on theta in (0,180) the thresholds
// t_j ~ sin(theta - 30j) are monotone indicators: [bin >= j] <=> [t_j >= 0].
// So instead of an integer bin + 6-way deposit chain (28 VALU), do 6
// predicated adds into cumulative sums s_j (16 VALU). gy==0 forces bin 0
// (all s_1..s_5 conditions off); gx==0 falls out naturally (t3=-0>=0 etc
// gives the bin-3 pattern). Comparison-for-comparison identical binning.
__device__ __forceinline__ void hot_pixel(float gy, float gx, int bitk,
                                          float s[NORI], unsigned& ambmask) {
    const float mag = __fsqrt_rn(__fmaf_rn(gy, gy, __fmul_rn(gx, gx)));
    // canonicalize to theta in [0,180)
    const bool neg = gy < 0.0f;
    const float cy = fabsf(gy);
    const float cx = neg ? -gx : gx;
    // t_i ~ sin(theta - alpha_i), alpha = 30,60,90,120,150 (shared products)
    const float pa = __fmul_rn(cy, 0.86602540378443864676f);
    const float pb = __fmul_rn(cx, 0.5f);
    const float pc = __fmul_rn(cy, 0.5f);
    const float pd = __fmul_rn(cx, 0.86602540378443864676f);
    const float t1 = __fsub_rn(pa, pb);
    const float t2 = __fsub_rn(pc, pd);
    const float t3 = -cx;
    const float t4 = -__fadd_rn(pc, pd);
    const float t5 = -__fadd_rn(pa, pb);
    const float sc = __fmul_rn(mag, 1e-5f);
    const float mn = fminf(fminf(fminf(fabsf(t1), fabsf(t2)),
                                 fminf(fabsf(t3), fabsf(t4))), fabsf(t5));
    const bool gyz = (gy == 0.0f);
    const bool gxz = (gx == 0.0f);
    bool amb = ((mn < sc) || (cx < 0.0f && cy < sc)) && !gyz && !gxz;
    ambmask |= amb ? (1u << bitk) : 0u;
    const float val = amb ? 0.0f : mag;
    const bool e = !gyz;
    s[0] += val;
    s[1] += (e & (t1 >= 0.0f)) ? val : 0.0f;
    s[2] += (e & (t2 >= 0.0f)) ? val : 0.0f;
    s[3] += (e & (t3 >= 0.0f)) ? val : 0.0f;
    s[4] += (e & (t4 >= 0.0f)) ? val : 0.0f;
    s[5] += (e & (t5 >= 0.0f)) ? val : 0.0f;
}

// Lane = 4 adjacent columns (float4 channel loads); wave = 256 cols x 4 rows;
// block = 4 waves = one 16-row cell-row x 256 cols (16 cells). Rolling 3-row
// float4 gray window; interior gx needs no shfl, quad edges use 2 shfls/row.
// Ambiguous pixels (within 1e-5 rad of a bin boundary) set a mask bit and are
// re-done post-loop with the round-5 atan2f +-2ulp policy from global memory.
__global__ __launch_bounds__(256) void hog_cells_kernel(const float* __restrict__ x,
                                                        float* __restrict__ cells) {
    const int b = blockIdx.z;
    const int tid = threadIdx.x;
    const int wave = tid >> 6, lane = tid & 63;
    const int by = blockIdx.y;              // cell row
    const int R0 = by * 16 + wave * 4;      // this wave's first pixel row
    const int C0 = blockIdx.x * 256;
    const int c0 = C0 + lane * 4;
    const float* img = x + (size_t)b * 3 * HH * WW;

    __shared__ float hist[16][NORI];
    if (tid < 16 * NORI) ((float*)hist)[tid] = 0.0f;
    __syncthreads();

    // single halo column per wave: left block needs abs col 256 (lane 63),
    // right block needs abs col 255 (lane 0). Image borders give gx=0 instead.
    const bool left_blk = (blockIdx.x == 0);
    const int hc = left_blk ? 256 : 255;
    const bool is_h = (lane == (left_blk ? 63 : 0));

    float4 gm1 = gray4(img, max(R0 - 1, 0) * WW + c0);
    float4 g0  = gray4(img, R0 * WW + c0);
    float hcur = is_h ? gray_i(img, R0 * WW + hc) : 0.0f;

    float s[NORI] = {0, 0, 0, 0, 0, 0};
    unsigned ambmask = 0;

#pragma unroll
    for (int k = 0; k < 4; ++k) {
        const int r = R0 + k;
        const int rn = min(r + 1, HH - 1);
        const float4 gp1 = gray4(img, rn * WW + c0);
        const float hnext = is_h ? gray_i(img, rn * WW + hc) : 0.0f;

        const bool row_ok = (r >= 1) && (r < HH - 1);
        const float gy0 = row_ok ? __fsub_rn(gp1.x, gm1.x) : 0.0f;
        const float gy1 = row_ok ? __fsub_rn(gp1.y, gm1.y) : 0.0f;
        const float gy2 = row_ok ? __fsub_rn(gp1.z, gm1.z) : 0.0f;
        const float gy3 = row_ok ? __fsub_rn(gp1.w, gm1.w) : 0.0f;

        float left  = __shfl(g0.w, (lane + 63) & 63);
        float right = __shfl(g0.x, (lane + 1) & 63);
        if (is_h) { if (left_blk) right = hcur; else left = hcur; }

        float gx0 = __fsub_rn(g0.y, left);
        const float gx1 = __fsub_rn(g0.z, g0.x);
        const float gx2 = __fsub_rn(g0.w, g0.y);
        float gx3 = __fsub_rn(right, g0.z);
        if (c0 == 0) gx0 = 0.0f;             // image left border
        if (c0 + 3 == WW - 1) gx3 = 0.0f;    // image right border

        hot_pixel(gy0, gx0, 4 * k + 0, s, ambmask);
        hot_pixel(gy1, gx1, 4 * k + 1, s, ambmask);
        hot_pixel(gy2, gx2, 4 * k + 2, s, ambmask);
        hot_pixel(gy3, gx3, 4 * k + 3, s, ambmask);

        gm1 = g0; g0 = gp1; hcur = hnext;
    }

    // cold phase: rare. amb pixels are interior with gy!=0 && gx!=0;
    // recompute bitwise-identically from global memory. Deposits go into the
    // same cumulative-sum representation (linear, order-free).
    if (__any(ambmask != 0)) {
        unsigned m = ambmask;
        while (m) {
            const int bit = __builtin_ctz(m);
            m &= m - 1;
            const int r = R0 + (bit >> 2);
            const int c = c0 + (bit & 3);
            const int off = r * WW + c;
            const float gy = __fsub_rn(gray_i(img, off + WW), gray_i(img, off - WW));
            const float gx = __fsub_rn(gray_i(img, off + 1), gray_i(img, off - 1));
            const float mag = __fsqrt_rn(__fmaf_rn(gy, gy, __fmul_rn(gx, gx)));
            const float a = atan2f(gy, gx);
            const int bl = bin_of(ulp_step(a, -2));
            const int bh = bin_of(ulp_step(a, +2));
            if (bl == bh) {
                deposit_s(s, bl, mag);
            } else {
                const int b0 = bin_of(a);
                const int bo = (b0 == bl) ? bh : bl;
                deposit_s(s, b0, __fmul_rn(mag, 0.65f));
                deposit_s(s, bo, __fmul_rn(mag, 0.35f));
            }
        }
    }

    // reduce the 4 lanes of each cell (16 cols = lanes 4c..4c+3); stays in
    // cumulative form (linear in the per-pixel deposits)
#pragma unroll
    for (int o = 0; o < NORI; ++o) {
        float v = s[o];
        v += __shfl_xor(v, 1);
        v += __shfl_xor(v, 2);
        s[o] = v;
    }
    if ((lane & 3) == 0) {
        const int cell = lane >> 2;
#pragma unroll
        for (int o = 0; o < NORI; ++o) atomicAdd(&hist[cell][o], s[o]);
    }
    __syncthreads();
    if (tid < 96) {
        const int cell = tid / 6, o = tid - cell * 6;
        const float hi = hist[cell][o];
        const float lo = (o < NORI - 1) ? hist[cell][o + 1] : 0.0f;
        cells[(((size_t)b * NC + by) * NC + ((C0 >> 4) + cell)) * NORI + o] =
            __fmul_rn(__fsub_rn(hi, lo), (1.0f / 256.0f));
    }
}

// One thread per (b, block_row, block_col): float2 loads, L2-Hys normalize.
__global__ __launch_bounds__(256) void hog_norm_kernel(const float* __restrict__ cells,
                                                       float* __restrict__ out) {
    const int idx = blockIdx.x * 256 + threadIdx.x;
    const int total = BATCH * 31 * 31;
    if (idx >= total) return;
    const int bc = idx % 31;
    const int t = idx / 31;
    const int br = t % 31;
    const int b = t / 31;

    const float* cb = cells + (size_t)b * NC * NC * NORI;
    const float2* p0 = (const float2*)(cb + ((br) * NC + bc) * NORI);
    const float2* p1 = (const float2*)(cb + ((br + 1) * NC + bc) * NORI);
    float v[24];
#pragma unroll
    for (int q = 0; q < 6; ++q) {
        const float2 r0 = p0[q], r1 = p1[q];
        v[2 * q] = r0.x; v[2 * q + 1] = r0.y;
        v[12 + 2 * q] = r1.x; v[12 + 2 * q + 1] = r1.y;
    }
    float ss = 0.0f;
#pragma unroll
    for (int k = 0; k < 24; ++k) ss = __fadd_rn(ss, __fmul_rn(v[k], v[k]));
    const float n1 = __fsqrt_rn(__fadd_rn(ss, 1e-10f));  // EPS^2, EPS=1e-5
    float ss2 = 0.0f;
#pragma unroll
    for (int k = 0; k < 24; ++k) {
        v[k] = fminf(__fdiv_rn(v[k], n1), 0.2f);
        ss2 = __fadd_rn(ss2, __fmul_rn(v[k], v[k]));
    }
    const float n2 = __fsqrt_rn(__fadd_rn(ss2, 1e-10f));
    float* op = out + (size_t)idx * 24;
#pragma unroll
    for (int k = 0; k < 24; ++k) op[k] = __fdiv_rn(v[k], n2);
}

extern "C" void kernel_launch(void* const* d_in, const int* in_sizes, int n_in,
                              void* d_out, int out_size, void* d_ws, size_t ws_size,
                              hipStream_t stream) {
    const float* x = (const float*)d_in[0];
    float* out = (float*)d_out;
    float* cells = (float*)d_ws;  // BATCH*32*32*6 floats = 786 KB

    dim3 g1(2, NC, BATCH), b1(256);
    hog_cells_kernel<<<g1, b1, 0, stream>>>(x, cells);

    const int total = BATCH * 31 * 31;
    hog_norm_kernel<<<(total + 255) / 256, 256, 0, stream>>>(cells, out);
}

// Round 3
// 152.140 us; speedup vs baseline: 1.0303x; 1.0101x over previous
//
#include <hip/hip_runtime.h>
#include <math.h>

#define BATCH 32
#define HH 512
#define WW 512
#define NC 32        // cells per side
#define NORI 6
#define CH 262144    // HH*WW channel stride (floats)

// ---- round-5-verbatim numpy downstream (cold path, ONE inline copy) ----
__device__ __forceinline__ int bin_of(float a) {
    const float deg = __fmul_rn(a, 57.29577951308232f);
    float m = fmodf(deg, 180.0f);
    if (m < 0.0f) m = __fadd_rn(m, 180.0f);
    const int b = (int)floorf(__fdiv_rn(m, 30.0f));
    return min(max(b, 0), NORI - 1);
}
__device__ __forceinline__ float ulp_step(float x, int k) {
    const int i = __float_as_int(x);
    int key = (i >= 0) ? i : -(i & 0x7FFFFFFF);
    key += k;
    const int r = (key >= 0) ? key : (int)(0x80000000u | (unsigned)(-key));
    return __int_as_float(r);
}
__device__ __forceinline__ void deposit(float acc[NORI], int bin, float val) {
#pragma unroll
    for (int o = 0; o < NORI; ++o) acc[o] += (bin == o) ? val : 0.0f;
}
// (0.299*R + 0.587*G) + 0.114*B, f32, no FMA contraction
__device__ __forceinline__ float gray_comb(float r, float g, float b) {
    return __fadd_rn(__fadd_rn(__fmul_rn(0.299f, r), __fmul_rn(0.587f, g)),
                     __fmul_rn(0.114f, b));
}
__device__ __forceinline__ float gray_i(const float* __restrict__ img, int off) {
    return gray_comb(img[off], img[off + CH], img[off + 2 * CH]);
}
__device__ __forceinline__ float4 gray4(const float* __restrict__ img, int off) {
    const float4 r = *(const float4*)(img + off);
    const float4 g = *(const float4*)(img + off + CH);
    const float4 b = *(const float4*)(img + off + 2 * CH);
    float4 o;
    o.x = gray_comb(r.x, g.x, b.x);
    o.y = gray_comb(r.y, g.y, b.y);
    o.z = gray_comb(r.z, g.z, b.z);
    o.w = gray_comb(r.w, g.w, b.w);
    return o;
}

__device__ __forceinline__ void hot_pixel(float gy, float gx, int bitk,
                                          float acc[NORI], unsigned& ambmask) {
    const float mag = __fsqrt_rn(__fmaf_rn(gy, gy, __fmul_rn(gx, gx)));
    // canonicalize to theta in [0,180)
    const bool neg = gy < 0.0f;
    const float cy = fabsf(gy);
    const float cx = neg ? -gx : gx;
    // t_i ~ sin(theta - alpha_i), alpha = 30,60,90,120,150 (shared products)
    const float pa = __fmul_rn(cy, 0.86602540378443864676f);
    const float pb = __fmul_rn(cx, 0.5f);
    const float pc = __fmul_rn(cy, 0.5f);
    const float pd = __fmul_rn(cx, 0.86602540378443864676f);
    const float t1 = __fsub_rn(pa, pb);
    const float t2 = __fsub_rn(pc, pd);
    const float t3 = -cx;
    const float t4 = -__fadd_rn(pc, pd);
    const float t5 = -__fadd_rn(pa, pb);
    int bin = (t1 >= 0.0f) + (t2 >= 0.0f) + (t3 >= 0.0f) +
              (t4 >= 0.0f) + (t5 >= 0.0f);
    const float s = __fmul_rn(mag, 1e-5f);
    const float mn = fminf(fminf(fminf(fabsf(t1), fabsf(t2)),
                                 fminf(fabsf(t3), fabsf(t4))), fabsf(t5));
    bool amb = (mn < s) || (cx < 0.0f && cy < s);   // incl. wrap at 180
    if (gy == 0.0f) { bin = 0; amb = false; }       // deterministic (r3/r5)
    else if (gx == 0.0f) { bin = 3; amb = false; }
    ambmask |= amb ? (1u << bitk) : 0u;
    deposit(acc, bin, amb ? 0.0f : mag);
}

// Lane = 4 adjacent columns (float4 channel loads); wave = 256 cols x 4 rows;
// block = 4 waves = one 16-row cell-row x 256 cols (16 cells). Rolling 3-row
// float4 gray window; interior gx needs no shfl, quad edges use 2 shfls/row.
// Ambiguous pixels (within 1e-5 rad of a bin boundary) set a mask bit and are
// re-done post-loop with the round-5 atan2f +-2ulp policy from global memory.
// __launch_bounds__(256, 8): cap VGPR at 64 so all 8 blocks/CU are resident
// (32 waves/CU) — occupancy-latency probe; r1/r2 ruled out VALU and structure.
__global__ __launch_bounds__(256, 8) void hog_cells_kernel(const float* __restrict__ x,
                                                           float* __restrict__ cells) {
    const int b = blockIdx.z;
    const int tid = threadIdx.x;
    const int wave = tid >> 6, lane = tid & 63;
    const int by = blockIdx.y;              // cell row
    const int R0 = by * 16 + wave * 4;      // this wave's first pixel row
    const int C0 = blockIdx.x * 256;
    const int c0 = C0 + lane * 4;
    const float* img = x + (size_t)b * 3 * HH * WW;

    __shared__ float hist[16][NORI];
    if (tid < 16 * NORI) ((float*)hist)[tid] = 0.0f;
    __syncthreads();

    // single halo column per wave: left block needs abs col 256 (lane 63),
    // right block needs abs col 255 (lane 0). Image borders give gx=0 instead.
    const bool left_blk = (blockIdx.x == 0);
    const int hc = left_blk ? 256 : 255;
    const bool is_h = (lane == (left_blk ? 63 : 0));

    float4 gm1 = gray4(img, max(R0 - 1, 0) * WW + c0);
    float4 g0  = gray4(img, R0 * WW + c0);
    float hcur = is_h ? gray_i(img, R0 * WW + hc) : 0.0f;

    float acc[NORI] = {0, 0, 0, 0, 0, 0};
    unsigned ambmask = 0;

#pragma unroll
    for (int k = 0; k < 4; ++k) {
        const int r = R0 + k;
        const int rn = min(r + 1, HH - 1);
        const float4 gp1 = gray4(img, rn * WW + c0);
        const float hnext = is_h ? gray_i(img, rn * WW + hc) : 0.0f;

        const bool row_ok = (r >= 1) && (r < HH - 1);
        const float gy0 = row_ok ? __fsub_rn(gp1.x, gm1.x) : 0.0f;
        const float gy1 = row_ok ? __fsub_rn(gp1.y, gm1.y) : 0.0f;
        const float gy2 = row_ok ? __fsub_rn(gp1.z, gm1.z) : 0.0f;
        const float gy3 = row_ok ? __fsub_rn(gp1.w, gm1.w) : 0.0f;

        float left  = __shfl(g0.w, (lane + 63) & 63);
        float right = __shfl(g0.x, (lane + 1) & 63);
        if (is_h) { if (left_blk) right = hcur; else left = hcur; }

        float gx0 = __fsub_rn(g0.y, left);
        const float gx1 = __fsub_rn(g0.z, g0.x);
        const float gx2 = __fsub_rn(g0.w, g0.y);
        float gx3 = __fsub_rn(right, g0.z);
        if (c0 == 0) gx0 = 0.0f;             // image left border
        if (c0 + 3 == WW - 1) gx3 = 0.0f;    // image right border

        hot_pixel(gy0, gx0, 4 * k + 0, acc, ambmask);
        hot_pixel(gy1, gx1, 4 * k + 1, acc, ambmask);
        hot_pixel(gy2, gx2, 4 * k + 2, acc, ambmask);
        hot_pixel(gy3, gx3, 4 * k + 3, acc, ambmask);

        gm1 = g0; g0 = gp1; hcur = hnext;
    }

    // cold phase: rare. amb pixels are interior with gy!=0 && gx!=0;
    // recompute bitwise-identically from global memory.
    if (__any(ambmask != 0)) {
        unsigned m = ambmask;
        while (m) {
            const int bit = __builtin_ctz(m);
            m &= m - 1;
            const int r = R0 + (bit >> 2);
            const int c = c0 + (bit & 3);
            const int off = r * WW + c;
            const float gy = __fsub_rn(gray_i(img, off + WW), gray_i(img, off - WW));
            const float gx = __fsub_rn(gray_i(img, off + 1), gray_i(img, off - 1));
            const float mag = __fsqrt_rn(__fmaf_rn(gy, gy, __fmul_rn(gx, gx)));
            const float a = atan2f(gy, gx);
            const int bl = bin_of(ulp_step(a, -2));
            const int bh = bin_of(ulp_step(a, +2));
            if (bl == bh) {
                deposit(acc, bl, mag);
            } else {
                const int b0 = bin_of(a);
                const int bo = (b0 == bl) ? bh : bl;
                deposit(acc, b0, __fmul_rn(mag, 0.65f));
                deposit(acc, bo, __fmul_rn(mag, 0.35f));
            }
        }
    }

    // reduce the 4 lanes of each cell (16 cols = lanes 4c..4c+3)
#pragma unroll
    for (int o = 0; o < NORI; ++o) {
        float v = acc[o];
        v += __shfl_xor(v, 1);
        v += __shfl_xor(v, 2);
        acc[o] = v;
    }
    if ((lane & 3) == 0) {
        const int cell = lane >> 2;
#pragma unroll
        for (int o = 0; o < NORI; ++o) atomicAdd(&hist[cell][o], acc[o]);
    }
    __syncthreads();
    if (tid < 96) {
        const int cell = tid / 6, o = tid - cell * 6;
        cells[(((size_t)b * NC + by) * NC + ((C0 >> 4) + cell)) * NORI + o] =
            hist[cell][o] * (1.0f / 256.0f);
    }
}

// One thread per (b, block_row, block_col): float2 loads, L2-Hys normalize.
__global__ __launch_bounds__(256) void hog_norm_kernel(const float* __restrict__ cells,
                                                       float* __restrict__ out) {
    const int idx = blockIdx.x * 256 + threadIdx.x;
    const int total = BATCH * 31 * 31;
    if (idx >= total) return;
    const int bc = idx % 31;
    const int t = idx / 31;
    const int br = t % 31;
    const int b = t / 31;

    const float* cb = cells + (size_t)b * NC * NC * NORI;
    const float2* p0 = (const float2*)(cb + ((br) * NC + bc) * NORI);
    const float2* p1 = (const float2*)(cb + ((br + 1) * NC + bc) * NORI);
    float v[24];
#pragma unroll
    for (int q = 0; q < 6; ++q) {
        const float2 r0 = p0[q], r1 = p1[q];
        v[2 * q] = r0.x; v[2 * q + 1] = r0.y;
        v[12 + 2 * q] = r1.x; v[12 + 2 * q + 1] = r1.y;
    }
    float ss = 0.0f;
#pragma unroll
    for (int k = 0; k < 24; ++k) ss = __fadd_rn(ss, __fmul_rn(v[k], v[k]));
    const float n1 = __fsqrt_rn(__fadd_rn(ss, 1e-10f));  // EPS^2, EPS=1e-5
    float ss2 = 0.0f;
#pragma unroll
    for (int k = 0; k < 24; ++k) {
        v[k] = fminf(__fdiv_rn(v[k], n1), 0.2f);
        ss2 = __fadd_rn(ss2, __fmul_rn(v[k], v[k]));
    }
    const float n2 = __fsqrt_rn(__fadd_rn(ss2, 1e-10f));
    float* op = out + (size_t)idx * 24;
#pragma unroll
    for (int k = 0; k < 24; ++k) op[k] = __fdiv_rn(v[k], n2);
}

extern "C" void kernel_launch(void* const* d_in, const int* in_sizes, int n_in,
                              void* d_out, int out_size, void* d_ws, size_t ws_size,
                              hipStream_t stream) {
    const float* x = (const float*)d_in[0];
    float* out = (float*)d_out;
    float* cells = (float*)d_ws;  // BATCH*32*32*6 floats = 786 KB

    dim3 g1(2, NC, BATCH), b1(256);
    hog_cells_kernel<<<g1, b1, 0, stream>>>(x, cells);

    const int total = BATCH * 31 * 31;
    hog_norm_kernel<<<(total + 255) / 256, 256, 0, stream>>>(cells, out);
}